// Round 1
// baseline (169.664 us; speedup 1.0000x reference)
//
#include <hip/hip_runtime.h>
#include <math.h>

#define VOCAB 2048
#define TPB   256
#define RPB   4            // rows (waves) per block
#define NBINS 64
// 64 bins cover (m - v) in [0, 64/6 = 10.667); kept tokens provably have
// m - v <= ln(2048/0.05) = 10.62, so the top-p crossing is always inside.
#define BIN_SCALE 6.0f
#define CAP   512          // shared compaction capacity per row (boundary & kept)

typedef float vf4 __attribute__((ext_vector_type(4)));

// One wave (64 lanes) per row, 32 elements per lane, ZERO block barriers.
// All reductions are in-wave shfl butterflies; LDS segments are wave-private
// (same-wave DS ordering makes them coherent without __syncthreads).
__global__ __launch_bounds__(TPB, 4) void sampler_kernel(
    const float* __restrict__ logits,
    const float* __restrict__ uni,
    float* __restrict__ out_idx,    // [B]   sampled index as float
    float* __restrict__ out_probs)  // [B,V] filtered softmax
{
    const int lane = threadIdx.x & 63;
    const int wid  = threadIdx.x >> 6;
    const int row  = (blockIdx.x << 2) | wid;

    __shared__ float s_bins[RPB][NBINS];
    __shared__ float s_cv[RPB][CAP];   // phase A: boundary values; phase B: kept values
    __shared__ float s_ci[RPB][CAP];   // phase A: boundary exps;   phase B: kept idx (bits)
    __shared__ int   s_bcnt[RPB];
    __shared__ int   s_kcnt[RPB];

    const float* lrow = logits    + (size_t)row * VOCAB;
    const float* urow = uni       + (size_t)row * VOCAB;
    float*       prow = out_probs + (size_t)row * VOCAB;

    // wave-private LDS init (1 bin per lane)
    s_bins[wid][lane] = 0.0f;
    if (lane == 0) { s_bcnt[wid] = 0; s_kcnt[wid] = 0; }

    // ---- load + temperature scale (x*1.25f ~ x/0.8f to ~1 ulp) ----
    float s[32];
    #pragma unroll
    for (int j = 0; j < 8; j++) {
        vf4 a = __builtin_nontemporal_load((const vf4*)(lrow + j * 256 + 4 * lane));
        s[4*j+0] = a.x * 1.25f;
        s[4*j+1] = a.y * 1.25f;
        s[4*j+2] = a.z * 1.25f;
        s[4*j+3] = a.w * 1.25f;
    }

    // ---- wave max (butterfly -> all lanes) ----
    float m0 = s[0], m1 = s[1], m2 = s[2], m3 = s[3];
    #pragma unroll
    for (int j = 4; j < 32; j += 4) {
        m0 = fmaxf(m0, s[j+0]); m1 = fmaxf(m1, s[j+1]);
        m2 = fmaxf(m2, s[j+2]); m3 = fmaxf(m3, s[j+3]);
    }
    float m = fmaxf(fmaxf(m0, m1), fmaxf(m2, m3));
    #pragma unroll
    for (int off = 32; off; off >>= 1)
        m = fmaxf(m, __shfl_xor(m, off));

    // ---- exp (fast), total sum (double), exp-mass histogram by value bin ----
    float e[32];
    double p0 = 0.0, p1 = 0.0;
    #pragma unroll
    for (int j = 0; j < 32; j++) {
        e[j] = __expf(s[j] - m);
        if (j & 1) p1 += (double)e[j]; else p0 += (double)e[j];
        int b = (int)((m - s[j]) * BIN_SCALE);
        if (b < NBINS) atomicAdd(&s_bins[wid][b], e[j]);
    }
    double dp = p0 + p1;
    #pragma unroll
    for (int off = 32; off; off >>= 1)
        dp += __shfl_xor(dp, off);
    const double S  = dp;
    const double pS = 0.95 * S;

    // ---- in-wave prefix scan of the 64 bins (1 bin per lane), find boundary ----
    const float bf = s_bins[wid][lane];      // same-wave DS order: atomics done
    double c = (double)bf;
    #pragma unroll
    for (int d = 1; d < 64; d <<= 1) {
        double o = __shfl_up(c, d);
        if (lane >= d) c += o;
    }
    const unsigned long long ball = __ballot(c > pS);
    const int bstar = ball ? (__ffsll(ball) - 1) : (NBINS - 1);
    double excl = c - (double)bf;            // exclusive prefix
    const double cumBefore = __shfl(excl, bstar);

    // ---- compact boundary-bin candidates to wave-private LDS ----
    #pragma unroll
    for (int j = 0; j < 32; j++) {
        int b = (int)((m - s[j]) * BIN_SCALE);
        if (b == bstar) {
            int pos = atomicAdd(&s_bcnt[wid], 1);
            if (pos < CAP) { s_cv[wid][pos] = s[j]; s_ci[wid][pos] = e[j]; }
        }
    }
    const int bcnt = min(s_bcnt[wid], CAP);

    // ---- keep decision: kept <=> exp-sum over strictly-greater values <= p*S ----
    unsigned keptMask = 0;
    float k0 = 0.0f, k1 = 0.0f;
    #pragma unroll
    for (int j = 0; j < 32; j++) {
        int b = (int)((m - s[j]) * BIN_SCALE);
        bool kept;
        if (b < bstar)      kept = true;
        else if (b > bstar) kept = false;
        else {
            float part = 0.0f;
            for (int i = 0; i < bcnt; i++)
                if (s_cv[wid][i] > s[j]) part += s_ci[wid][i];  // broadcast reads
            kept = (cumBefore + (double)part) <= pS;
        }
        if (kept) {
            keptMask |= (1u << j);
            if (j & 1) k1 += e[j]; else k0 += e[j];
        }
    }
    float kpsum = k0 + k1;
    #pragma unroll
    for (int off = 32; off; off >>= 1)
        kpsum += __shfl_xor(kpsum, off);
    const float invSK = 1.0f / kpsum;

    // ---- write probs (nontemporal: never re-read) ----
    #pragma unroll
    for (int j = 0; j < 8; j++) {
        vf4 p;
        p.x = ((keptMask >> (4*j+0)) & 1u) ? e[4*j+0] * invSK : 0.0f;
        p.y = ((keptMask >> (4*j+1)) & 1u) ? e[4*j+1] * invSK : 0.0f;
        p.z = ((keptMask >> (4*j+2)) & 1u) ? e[4*j+2] * invSK : 0.0f;
        p.w = ((keptMask >> (4*j+3)) & 1u) ? e[4*j+3] * invSK : 0.0f;
        __builtin_nontemporal_store(p, (vf4*)(prow + j * 256 + 4 * lane));
    }

    // ---- compact KEPT tokens (value, idx); exact in-register fallback on overflow ----
    unsigned ovf = 0;
    #pragma unroll
    for (int j = 0; j < 32; j++) {
        if ((keptMask >> j) & 1u) {
            int pos = atomicAdd(&s_kcnt[wid], 1);
            if (pos < CAP) {
                s_cv[wid][pos] = s[j];
                s_ci[wid][pos] = __int_as_float((j >> 2) * 256 + 4 * lane + (j & 3));
            } else {
                ovf |= (1u << j);
            }
        }
    }
    const int kc = min(s_kcnt[wid], CAP);

    // ---- Gumbel-max over kept tokens (precise logf, sparse u gather) ----
    unsigned long long key = 0ull;   // any real z maps above 0
    for (int i = lane; i < kc; i += 64) {
        float sv  = s_cv[wid][i];
        int   idx = __float_as_int(s_ci[wid][i]);
        float uv  = urow[idx];
        float g   = -logf(-logf(uv));
        float z   = sv + g;
        unsigned zb = __float_as_uint(z);
        zb = (zb & 0x80000000u) ? ~zb : (zb | 0x80000000u);  // order-preserving map
        unsigned long long kk =
            ((unsigned long long)zb << 32) | (unsigned)(VOCAB - 1 - idx); // min-idx tiebreak
        key = (kk > key) ? kk : key;
    }
    if (__builtin_expect(ovf != 0, 0)) {      // cold exact path: row had >CAP kept
        #pragma unroll
        for (int j = 0; j < 32; j++) {
            if ((ovf >> j) & 1u) {
                int   idx = (j >> 2) * 256 + 4 * lane + (j & 3);
                float uv  = urow[idx];
                float g   = -logf(-logf(uv));
                float z   = s[j] + g;
                unsigned zb = __float_as_uint(z);
                zb = (zb & 0x80000000u) ? ~zb : (zb | 0x80000000u);
                unsigned long long kk =
                    ((unsigned long long)zb << 32) | (unsigned)(VOCAB - 1 - idx);
                key = (kk > key) ? kk : key;
            }
        }
    }
    #pragma unroll
    for (int off = 32; off; off >>= 1) {
        unsigned long long ok = __shfl_xor(key, off);
        key = (ok > key) ? ok : key;
    }
    if (lane == 0)
        out_idx[row] = (float)(VOCAB - 1 - (int)(key & 0xFFFFFFFFu));
}

extern "C" void kernel_launch(void* const* d_in, const int* in_sizes, int n_in,
                              void* d_out, int out_size, void* d_ws, size_t ws_size,
                              hipStream_t stream) {
    const float* logits = (const float*)d_in[0];
    const float* u      = (const float*)d_in[1];
    const int B = in_sizes[0] / VOCAB;   // 8192
    float* out_idx   = (float*)d_out;          // sampled [B,1] flattened
    float* out_probs = (float*)d_out + B;      // probs [B,V]
    sampler_kernel<<<B / RPB, TPB, 0, stream>>>(logits, u, out_idx, out_probs);
}